// Round 1
// baseline (103.374 us; speedup 1.0000x reference)
//
#include <hip/hip_runtime.h>
#include <cstdint>
#include <cstddef>

#define B_ 8
#define C_ 10
#define HW_ 65536
#define NPIX_ (B_ * HW_)

__device__ __forceinline__ float xprod(float ux, float uy, float vx, float vy) {
    return ux * vy - uy * vx;
}

// order-preserving float -> uint32 key (ascending float order -> ascending uint order)
__device__ __forceinline__ uint32_t okey(float f) {
    uint32_t b = __float_as_uint(f);
    return (b & 0x80000000u) ? ~b : (b | 0x80000000u);
}

__device__ __forceinline__ float sl1f(float p, float t) {
    float d = fabsf(p - t);
    return (d < 1.0f) ? 0.5f * d * d : d - 0.5f;
}

__global__ __launch_bounds__(256) void bev_loss_main(
    const float* __restrict__ cls_pred, const float* __restrict__ reg_pred,
    const float* __restrict__ iou_pred, const int* __restrict__ cls_tg,
    const float* __restrict__ reg_tg, const float* __restrict__ reg_w,
    const float* __restrict__ iou_tg, double* __restrict__ part)
{
    double acc0 = 0, acc1 = 0, acc2 = 0, acc3 = 0, acc4 = 0, acc5 = 0, acc6 = 0;
    int stride = gridDim.x * blockDim.x;
    for (int n = blockIdx.x * blockDim.x + threadIdx.x; n < NPIX_; n += stride) {
        int b  = n >> 16;
        int hw = n & 65535;

        // ---------------- classification focal loss ----------------
        {
            const float* cp = cls_pred + (size_t)b * C_ * HW_ + hw;
            float lg[C_];
            #pragma unroll
            for (int c = 0; c < C_; c++) lg[c] = cp[(size_t)c * HW_];
            int ct = cls_tg[n];
            float m = lg[0];
            #pragma unroll
            for (int c = 1; c < C_; c++) m = fmaxf(m, lg[c]);
            float se = 0.f;
            #pragma unroll
            for (int c = 0; c < C_; c++) se += expf(lg[c] - m);
            int tl = ct < 0 ? 0 : (ct > C_ - 1 ? C_ - 1 : ct);
            float pt = expf(lg[tl] - m) / se;
            pt = fminf(fmaxf(pt, 1e-7f), 1.0f - 1e-7f);
            float alpha_t = (ct > 0) ? 0.25f : 0.75f;
            float omp = 1.0f - pt;
            float fl = -alpha_t * omp * omp * logf(pt);
            float vmask = (ct >= 0) ? 1.0f : 0.0f;
            acc0 += (double)(fl * vmask);
        }

        // ---------------- regression channels ----------------
        float P[9], T[9];
        {
            const float* rp = reg_pred + (size_t)b * 9 * HW_ + hw;
            const float* rt = reg_tg  + (size_t)b * 9 * HW_ + hw;
            #pragma unroll
            for (int k = 0; k < 9; k++) { P[k] = rp[(size_t)k * HW_]; T[k] = rt[(size_t)k * HW_]; }
        }
        float w = reg_w[n];
        float pos = (w > 0.f) ? 1.f : 0.f;

        // ---------------- corners (reference order: reversed base) ----------------
        float Ax[4], Ay[4], Bx[4], By[4];
        {
            const float sbx[4] = { 1.f, -1.f, -1.f, 1.f };
            const float sby[4] = { -1.f, -1.f, 1.f, 1.f };
            float hx = 0.5f * P[3], hy = 0.5f * P[4];
            float cc = cosf(P[6]), ss = sinf(P[6]);
            #pragma unroll
            for (int i = 0; i < 4; i++) {
                float px = sbx[i] * hx, py = sby[i] * hy;
                Ax[i] = px * cc - py * ss + P[0];
                Ay[i] = px * ss + py * cc + P[1];
            }
            float hx2 = 0.5f * T[3], hy2 = 0.5f * T[4];
            float cc2 = cosf(T[6]), ss2 = sinf(T[6]);
            #pragma unroll
            for (int i = 0; i < 4; i++) {
                float px = sbx[i] * hx2, py = sby[i] * hy2;
                Bx[i] = px * cc2 - py * ss2 + T[0];
                By[i] = px * ss2 + py * cc2 + T[1];
            }
        }

        // signed areas + signs
        float sa = 0.f, sb = 0.f;
        #pragma unroll
        for (int i = 0; i < 4; i++) {
            int j = (i + 1) & 3;
            sa += xprod(Ax[i], Ay[i], Ax[j], Ay[j]);
            sb += xprod(Bx[i], By[i], Bx[j], By[j]);
        }
        sa *= 0.5f; sb *= 0.5f;
        float sgnA = (sa > 0.f) ? 1.f : ((sa < 0.f) ? -1.f : 0.f);
        float sgnB = (sb > 0.f) ? 1.f : ((sb < 0.f) ? -1.f : 0.f);

        // ---------------- rotated IoU candidates ----------------
        float qx[24], qy[24], qm[24];
        // A corners inside B (idx 0..3)
        #pragma unroll
        for (int i = 0; i < 4; i++) {
            bool in = true;
            #pragma unroll
            for (int j = 0; j < 4; j++) {
                int j1 = (j + 1) & 3;
                float ex = Bx[j1] - Bx[j], ey = By[j1] - By[j];
                float cr = xprod(ex, ey, Ax[i] - Bx[j], Ay[i] - By[j]);
                in = in && (cr * sgnB >= -1e-9f);
            }
            qx[i] = Ax[i]; qy[i] = Ay[i]; qm[i] = in ? 1.f : 0.f;
        }
        // B corners inside A (idx 4..7)
        #pragma unroll
        for (int i = 0; i < 4; i++) {
            bool in = true;
            #pragma unroll
            for (int j = 0; j < 4; j++) {
                int j1 = (j + 1) & 3;
                float ex = Ax[j1] - Ax[j], ey = Ay[j1] - Ay[j];
                float cr = xprod(ex, ey, Bx[i] - Ax[j], By[i] - Ay[j]);
                in = in && (cr * sgnA >= -1e-9f);
            }
            qx[4 + i] = Bx[i]; qy[4 + i] = By[i]; qm[4 + i] = in ? 1.f : 0.f;
        }
        // edge intersections (idx 8 + i*4 + j)
        #pragma unroll
        for (int i = 0; i < 4; i++) {
            int i1 = (i + 1) & 3;
            float dax = Ax[i1] - Ax[i], day = Ay[i1] - Ay[i];
            #pragma unroll
            for (int j = 0; j < 4; j++) {
                int j1 = (j + 1) & 3;
                float dbx = Bx[j1] - Bx[j], dby = By[j1] - By[j];
                float dpx = Bx[j] - Ax[i], dpy = By[j] - Ay[i];
                float den = xprod(dax, day, dbx, dby);
                float adn = fabsf(den);
                float dens = (adn < 1e-12f) ? 1.0f : den;
                float t = xprod(dpx, dpy, dbx, dby) / dens;
                float s = xprod(dpx, dpy, dax, day) / dens;
                bool v = (adn > 1e-12f) && (t >= 0.f) && (t <= 1.f) && (s >= 0.f) && (s <= 1.f);
                int id = 8 + i * 4 + j;
                qx[id] = Ax[i] + t * dax;
                qy[id] = Ay[i] + t * day;
                qm[id] = v ? 1.f : 0.f;
            }
        }

        // centroid over valid points
        float nvf = 0.f, sx = 0.f, sy = 0.f;
        #pragma unroll
        for (int k = 0; k < 24; k++) { nvf += qm[k]; sx += qm[k] * qx[k]; sy += qm[k] * qy[k]; }
        float denc = fmaxf(nvf, 1.0f);
        float cx = sx / denc, cy = sy / denc;

        // angle keys (invalid -> max key, matching key=1e9 sorted last; stable via
        // ascending-index first-win in the scans below)
        uint32_t qk[24];
        #pragma unroll
        for (int k = 0; k < 24; k++) {
            float ax = (qm[k] > 0.f ? qx[k] : 0.f) - cx;
            float ay = (qm[k] > 0.f ? qy[k] : 0.f) - cy;
            float ang = atan2f(ay, ax);
            qk[k] = (qm[k] > 0.f) ? okey(ang) : 0xFFFFFFFFu;
        }

        // global min-key point (wrap target)
        uint32_t minK = 0xFFFFFFFFu; float mnpx = 0.f, mnpy = 0.f;
        #pragma unroll
        for (int k = 0; k < 24; k++) {
            bool c = qk[k] < minK;
            minK = c ? qk[k] : minK;
            mnpx = c ? qx[k] : mnpx;
            mnpy = c ? qy[k] : mnpy;
        }

        // shoelace via angular successor (equivalent to stable argsort + roll)
        float shl = 0.f;
        #pragma unroll
        for (int i = 0; i < 24; i++) {
            uint32_t Ki = qk[i];
            uint32_t bK = 0xFFFFFFFFu; float bx = 0.f, by = 0.f;
            #pragma unroll
            for (int j = 0; j < 24; j++) {
                if (j == i) continue;
                bool gt = (j > i) ? (qk[j] >= Ki) : (qk[j] > Ki);
                bool c = gt && (qk[j] < bK);  // first-win on ties = smallest index
                bK = c ? qk[j] : bK;
                bx = c ? qx[j] : bx;
                by = c ? qy[j] : by;
            }
            bool none = (bK == 0xFFFFFFFFu);
            float nx = none ? mnpx : bx;
            float ny = none ? mnpy : by;
            shl += qm[i] * xprod(qx[i], qy[i], nx, ny);
        }
        float inter = 0.5f * fabsf(shl);
        int nv = (int)nvf;
        if (nv < 3) inter = 0.f;

        float areaA = fabsf(sa), areaB = fabsf(sb);
        float uni = areaA + areaB - inter;
        float iou = (uni > 1e-7f) ? inter / uni : 0.f;

        // ---------------- DIoU-style bev loss ----------------
        float ddx = P[0] - T[0], ddy = P[1] - T[1];
        float d2 = ddx * ddx + ddy * ddy;
        float mnx = Ax[0], mxx = Ax[0], mny = Ay[0], mxy = Ay[0];
        #pragma unroll
        for (int i = 1; i < 4; i++) {
            mnx = fminf(mnx, Ax[i]); mxx = fmaxf(mxx, Ax[i]);
            mny = fminf(mny, Ay[i]); mxy = fmaxf(mxy, Ay[i]);
        }
        #pragma unroll
        for (int i = 0; i < 4; i++) {
            mnx = fminf(mnx, Bx[i]); mxx = fmaxf(mxx, Bx[i]);
            mny = fminf(mny, By[i]); mxy = fmaxf(mxy, By[i]);
        }
        float ex_ = mxx - mnx, ey_ = mxy - mny;
        float c2 = fmaxf(ex_ * ex_ + ey_ * ey_, 1e-7f);

        float atp = atanf(P[4] / fmaxf(P[3], 1e-7f));
        float att = atanf(T[4] / fmaxf(T[3], 1e-7f));
        float dv = atp - att;
        float v = 0.4052847345693511f * dv * dv;
        float alpha_c = v / (1.0f - iou + v + 1e-7f);
        float lbev = 1.0f - iou + d2 / c2 + alpha_c * v;
        acc1 += (double)(lbev * pos);

        // ---------------- smooth-L1 z / h / vel ----------------
        acc2 += (double)(sl1f(P[2], T[2]) * pos);
        acc3 += (double)(sl1f(P[5], T[5]) * pos);
        acc4 += (double)((sl1f(P[7], T[7]) + sl1f(P[8], T[8])) * pos);

        // ---------------- iou BCE ----------------
        {
            float x = iou_pred[n], y = iou_tg[n];
            float bce = fmaxf(x, 0.f) - x * y + log1pf(expf(-fabsf(x)));
            acc5 += (double)(bce * pos);
        }
        acc6 += (double)pos;
    }

    // ---------------- block reduction ----------------
    __shared__ double red[4][7];
    double a[7] = { acc0, acc1, acc2, acc3, acc4, acc5, acc6 };
    int lane = threadIdx.x & 63;
    int wv = threadIdx.x >> 6;
    #pragma unroll
    for (int k = 0; k < 7; k++) {
        double s = a[k];
        for (int off = 32; off > 0; off >>= 1) s += __shfl_down(s, off, 64);
        if (lane == 0) red[wv][k] = s;
    }
    __syncthreads();
    if (threadIdx.x == 0) {
        #pragma unroll
        for (int k = 0; k < 7; k++)
            part[(size_t)blockIdx.x * 7 + k] = red[0][k] + red[1][k] + red[2][k] + red[3][k];
    }
}

__global__ void bev_loss_fin(const double* __restrict__ part, float* __restrict__ out, int nb) {
    int l = threadIdx.x;  // 64 threads
    double s[7] = { 0, 0, 0, 0, 0, 0, 0 };
    for (int i = l; i < nb; i += 64) {
        #pragma unroll
        for (int k = 0; k < 7; k++) s[k] += part[(size_t)i * 7 + k];
    }
    #pragma unroll
    for (int k = 0; k < 7; k++) {
        for (int off = 32; off > 0; off >>= 1) s[k] += __shfl_down(s[k], off, 64);
    }
    if (l == 0) {
        double npos = fmax(s[6], 1.0);
        #pragma unroll
        for (int k = 0; k < 6; k++) out[k] = (float)(s[k] / npos);
    }
}

extern "C" void kernel_launch(void* const* d_in, const int* in_sizes, int n_in,
                              void* d_out, int out_size, void* d_ws, size_t ws_size,
                              hipStream_t stream) {
    const float* cls_pred = (const float*)d_in[0];
    const float* reg_pred = (const float*)d_in[1];
    const float* iou_pred = (const float*)d_in[2];
    const int*   cls_tg   = (const int*)d_in[3];
    const float* reg_tg   = (const float*)d_in[4];
    const float* reg_w    = (const float*)d_in[5];
    const float* iou_tg   = (const float*)d_in[6];
    float* out = (float*)d_out;
    double* part = (double*)d_ws;

    int nb = 512;
    size_t need = (size_t)nb * 7 * sizeof(double);
    if (ws_size < need) {
        nb = (int)(ws_size / (7 * sizeof(double)));
        if (nb < 1) nb = 1;
    }

    bev_loss_main<<<nb, 256, 0, stream>>>(cls_pred, reg_pred, iou_pred, cls_tg,
                                          reg_tg, reg_w, iou_tg, part);
    bev_loss_fin<<<1, 64, 0, stream>>>(part, out, nb);
}

// Round 2
// 41.511 us; speedup vs baseline: 2.4903x; 2.4903x over previous
//
#include <hip/hip_runtime.h>
#include <cstdint>
#include <cstddef>

#define B_ 8
#define C_ 10
#define HW_ 65536
#define NPIX_ (B_ * HW_)

__device__ __forceinline__ float sl1f(float p, float t) {
    float d = fabsf(p - t);
    return (d < 1.0f) ? 0.5f * d * d : d - 0.5f;
}

__global__ __launch_bounds__(256) void bev_loss_main(
    const float* __restrict__ cls_pred, const float* __restrict__ reg_pred,
    const float* __restrict__ iou_pred, const int* __restrict__ cls_tg,
    const float* __restrict__ reg_tg, const float* __restrict__ reg_w,
    const float* __restrict__ iou_tg, double* __restrict__ part)
{
    double acc0 = 0, acc1 = 0, acc2 = 0, acc3 = 0, acc4 = 0, acc5 = 0, acc6 = 0;
    int stride = gridDim.x * blockDim.x;
    for (int n = blockIdx.x * blockDim.x + threadIdx.x; n < NPIX_; n += stride) {
        int b  = n >> 16;
        int hw = n & 65535;

        // ---------------- classification focal loss ----------------
        {
            const float* cp = cls_pred + (size_t)b * C_ * HW_ + hw;
            float lg[C_];
            #pragma unroll
            for (int c = 0; c < C_; c++) lg[c] = cp[(size_t)c * HW_];
            int ct = cls_tg[n];
            float m = lg[0];
            #pragma unroll
            for (int c = 1; c < C_; c++) m = fmaxf(m, lg[c]);
            float se = 0.f;
            #pragma unroll
            for (int c = 0; c < C_; c++) se += expf(lg[c] - m);
            int tl = ct < 0 ? 0 : (ct > C_ - 1 ? C_ - 1 : ct);
            float pt = expf(lg[tl] - m) / se;
            pt = fminf(fmaxf(pt, 1e-7f), 1.0f - 1e-7f);
            float alpha_t = (ct > 0) ? 0.25f : 0.75f;
            float omp = 1.0f - pt;
            float fl = -alpha_t * omp * omp * logf(pt);
            float vmask = (ct >= 0) ? 1.0f : 0.0f;
            acc0 += (double)(fl * vmask);
        }

        // ---------------- regression channels ----------------
        float P[9], T[9];
        {
            const float* rp = reg_pred + (size_t)b * 9 * HW_ + hw;
            const float* rt = reg_tg  + (size_t)b * 9 * HW_ + hw;
            #pragma unroll
            for (int k = 0; k < 9; k++) { P[k] = rp[(size_t)k * HW_]; T[k] = rt[(size_t)k * HW_]; }
        }
        float w = reg_w[n];
        float pos = (w > 0.f) ? 1.f : 0.f;

        // ---------------- corners (reference order: reversed base) ----------------
        float Ax[4], Ay[4], Bx[4], By[4];
        {
            const float sbx[4] = { 1.f, -1.f, -1.f, 1.f };
            const float sby[4] = { -1.f, -1.f, 1.f, 1.f };
            float hx = 0.5f * P[3], hy = 0.5f * P[4];
            float ss, cc; __sincosf(P[6], &ss, &cc);
            #pragma unroll
            for (int i = 0; i < 4; i++) {
                float px = sbx[i] * hx, py = sby[i] * hy;
                Ax[i] = px * cc - py * ss + P[0];
                Ay[i] = px * ss + py * cc + P[1];
            }
            float hx2 = 0.5f * T[3], hy2 = 0.5f * T[4];
            float ss2, cc2; __sincosf(T[6], &ss2, &cc2);
            #pragma unroll
            for (int i = 0; i < 4; i++) {
                float px = sbx[i] * hx2, py = sby[i] * hy2;
                Bx[i] = px * cc2 - py * ss2 + T[0];
                By[i] = px * ss2 + py * cc2 + T[1];
            }
        }

        // signed areas + orientation signs
        float sa = 0.f, sb = 0.f;
        #pragma unroll
        for (int i = 0; i < 4; i++) {
            int j = (i + 1) & 3;
            sa += Ax[i] * Ay[j] - Ay[i] * Ax[j];
            sb += Bx[i] * By[j] - By[i] * Bx[j];
        }
        sa *= 0.5f; sb *= 0.5f;
        float sgnA = (sa > 0.f) ? 1.f : ((sa < 0.f) ? -1.f : 0.f);
        float sgnB = (sb > 0.f) ? 1.f : ((sb < 0.f) ? -1.f : 0.f);

        // ---------------- rotated IoU via Green's theorem edge clipping ----------
        // inside-distances: dB[j][i] = sgnB * cross(eB_j, A_i - B_j)  (>=0 inside)
        float dB[4][4], dA[4][4];
        #pragma unroll
        for (int j = 0; j < 4; j++) {
            int j1 = (j + 1) & 3;
            float ex = Bx[j1] - Bx[j], ey = By[j1] - By[j];
            #pragma unroll
            for (int i = 0; i < 4; i++)
                dB[j][i] = sgnB * (ex * (Ay[i] - By[j]) - ey * (Ax[i] - Bx[j]));
        }
        #pragma unroll
        for (int j = 0; j < 4; j++) {
            int j1 = (j + 1) & 3;
            float ex = Ax[j1] - Ax[j], ey = Ay[j1] - Ay[j];
            #pragma unroll
            for (int i = 0; i < 4; i++)
                dA[j][i] = sgnA * (ex * (By[i] - Ay[j]) - ey * (Bx[i] - Ax[j]));
        }

        float S = 0.f;
        // edges of A clipped against B's 4 halfplanes
        #pragma unroll
        for (int i = 0; i < 4; i++) {
            int i1 = (i + 1) & 3;
            float t0 = 0.f, t1 = 1.f;
            #pragma unroll
            for (int j = 0; j < 4; j++) {
                float d0 = dB[j][i], d1 = dB[j][i1];
                float den = d1 - d0;
                float t = __fdividef(-d0, den);
                if (den > 0.f)       t0 = fmaxf(t0, t);
                else if (den < 0.f)  t1 = fminf(t1, t);
                else if (d0 < 0.f)   t0 = 2.f;      // edge entirely outside this halfplane
            }
            S += (Ax[i] * Ay[i1] - Ay[i] * Ax[i1]) * fmaxf(t1 - t0, 0.f);
        }
        // edges of B clipped against A's 4 halfplanes
        #pragma unroll
        for (int i = 0; i < 4; i++) {
            int i1 = (i + 1) & 3;
            float t0 = 0.f, t1 = 1.f;
            #pragma unroll
            for (int j = 0; j < 4; j++) {
                float d0 = dA[j][i], d1 = dA[j][i1];
                float den = d1 - d0;
                float t = __fdividef(-d0, den);
                if (den > 0.f)       t0 = fmaxf(t0, t);
                else if (den < 0.f)  t1 = fminf(t1, t);
                else if (d0 < 0.f)   t0 = 2.f;
            }
            S += (Bx[i] * By[i1] - By[i] * Bx[i1]) * fmaxf(t1 - t0, 0.f);
        }
        float inter = 0.5f * fabsf(S);

        float areaA = fabsf(sa), areaB = fabsf(sb);
        float uni = areaA + areaB - inter;
        float iou = (uni > 1e-7f) ? inter / uni : 0.f;

        // ---------------- DIoU-style bev loss ----------------
        float ddx = P[0] - T[0], ddy = P[1] - T[1];
        float d2 = ddx * ddx + ddy * ddy;
        float mnx = Ax[0], mxx = Ax[0], mny = Ay[0], mxy = Ay[0];
        #pragma unroll
        for (int i = 1; i < 4; i++) {
            mnx = fminf(mnx, Ax[i]); mxx = fmaxf(mxx, Ax[i]);
            mny = fminf(mny, Ay[i]); mxy = fmaxf(mxy, Ay[i]);
        }
        #pragma unroll
        for (int i = 0; i < 4; i++) {
            mnx = fminf(mnx, Bx[i]); mxx = fmaxf(mxx, Bx[i]);
            mny = fminf(mny, By[i]); mxy = fmaxf(mxy, By[i]);
        }
        float ex_ = mxx - mnx, ey_ = mxy - mny;
        float c2 = fmaxf(ex_ * ex_ + ey_ * ey_, 1e-7f);

        float atp = atanf(P[4] / fmaxf(P[3], 1e-7f));
        float att = atanf(T[4] / fmaxf(T[3], 1e-7f));
        float dv = atp - att;
        float v = 0.4052847345693511f * dv * dv;
        float alpha_c = v / (1.0f - iou + v + 1e-7f);
        float lbev = 1.0f - iou + d2 / c2 + alpha_c * v;
        acc1 += (double)(lbev * pos);

        // ---------------- smooth-L1 z / h / vel ----------------
        acc2 += (double)(sl1f(P[2], T[2]) * pos);
        acc3 += (double)(sl1f(P[5], T[5]) * pos);
        acc4 += (double)((sl1f(P[7], T[7]) + sl1f(P[8], T[8])) * pos);

        // ---------------- iou BCE ----------------
        {
            float x = iou_pred[n], y = iou_tg[n];
            float bce = fmaxf(x, 0.f) - x * y + log1pf(expf(-fabsf(x)));
            acc5 += (double)(bce * pos);
        }
        acc6 += (double)pos;
    }

    // ---------------- block reduction ----------------
    __shared__ double red[4][7];
    double a[7] = { acc0, acc1, acc2, acc3, acc4, acc5, acc6 };
    int lane = threadIdx.x & 63;
    int wv = threadIdx.x >> 6;
    #pragma unroll
    for (int k = 0; k < 7; k++) {
        double s = a[k];
        for (int off = 32; off > 0; off >>= 1) s += __shfl_down(s, off, 64);
        if (lane == 0) red[wv][k] = s;
    }
    __syncthreads();
    if (threadIdx.x == 0) {
        #pragma unroll
        for (int k = 0; k < 7; k++)
            part[(size_t)blockIdx.x * 7 + k] = red[0][k] + red[1][k] + red[2][k] + red[3][k];
    }
}

__global__ void bev_loss_fin(const double* __restrict__ part, float* __restrict__ out, int nb) {
    int l = threadIdx.x;  // 64 threads
    double s[7] = { 0, 0, 0, 0, 0, 0, 0 };
    for (int i = l; i < nb; i += 64) {
        #pragma unroll
        for (int k = 0; k < 7; k++) s[k] += part[(size_t)i * 7 + k];
    }
    #pragma unroll
    for (int k = 0; k < 7; k++) {
        for (int off = 32; off > 0; off >>= 1) s[k] += __shfl_down(s[k], off, 64);
    }
    if (l == 0) {
        double npos = fmax(s[6], 1.0);
        #pragma unroll
        for (int k = 0; k < 6; k++) out[k] = (float)(s[k] / npos);
    }
}

extern "C" void kernel_launch(void* const* d_in, const int* in_sizes, int n_in,
                              void* d_out, int out_size, void* d_ws, size_t ws_size,
                              hipStream_t stream) {
    const float* cls_pred = (const float*)d_in[0];
    const float* reg_pred = (const float*)d_in[1];
    const float* iou_pred = (const float*)d_in[2];
    const int*   cls_tg   = (const int*)d_in[3];
    const float* reg_tg   = (const float*)d_in[4];
    const float* reg_w    = (const float*)d_in[5];
    const float* iou_tg   = (const float*)d_in[6];
    float* out = (float*)d_out;
    double* part = (double*)d_ws;

    int nb = 2048;  // 1 pixel per thread; occupancy now VGPR-limited, not grid-limited
    size_t need = (size_t)nb * 7 * sizeof(double);
    if (ws_size < need) {
        nb = (int)(ws_size / (7 * sizeof(double)));
        if (nb < 1) nb = 1;
    }

    bev_loss_main<<<nb, 256, 0, stream>>>(cls_pred, reg_pred, iou_pred, cls_tg,
                                          reg_tg, reg_w, iou_tg, part);
    bev_loss_fin<<<1, 64, 0, stream>>>(part, out, nb);
}

// Round 3
// 37.773 us; speedup vs baseline: 2.7367x; 1.0990x over previous
//
#include <hip/hip_runtime.h>
#include <cstdint>
#include <cstddef>

#define B_ 8
#define C_ 10
#define HW_ 65536
#define NPIX_ (B_ * HW_)

__device__ __forceinline__ float sl1f(float p, float t) {
    float d = fabsf(p - t);
    return (d < 1.0f) ? 0.5f * d * d : d - 0.5f;
}

// Full per-pixel loss: writes the 7 accumulator terms.
__device__ __forceinline__ void pixel_loss(
    const float lg[C_], int ct, const float P[9], const float T[9],
    float w, float xiou, float yiou, float o[7])
{
    // ---------------- classification focal loss ----------------
    float m = lg[0];
    #pragma unroll
    for (int c = 1; c < C_; c++) m = fmaxf(m, lg[c]);
    float se = 0.f;
    float ex[C_];
    #pragma unroll
    for (int c = 0; c < C_; c++) { ex[c] = __expf(lg[c] - m); se += ex[c]; }
    int tl = ct < 0 ? 0 : (ct > C_ - 1 ? C_ - 1 : ct);
    float et = 0.f;
    #pragma unroll
    for (int c = 0; c < C_; c++) et = (c == tl) ? ex[c] : et;
    float pt = __fdividef(et, se);
    pt = fminf(fmaxf(pt, 1e-7f), 1.0f - 1e-7f);
    float alpha_t = (ct > 0) ? 0.25f : 0.75f;
    float omp = 1.0f - pt;
    float fl = -alpha_t * omp * omp * __logf(pt);
    o[0] = (ct >= 0) ? fl : 0.0f;

    float pos = (w > 0.f) ? 1.f : 0.f;

    // ---------------- corners (reference order: reversed base) ----------------
    float Ax[4], Ay[4], Bx[4], By[4];
    {
        const float sbx[4] = { 1.f, -1.f, -1.f, 1.f };
        const float sby[4] = { -1.f, -1.f, 1.f, 1.f };
        float hx = 0.5f * P[3], hy = 0.5f * P[4];
        float ss, cc; __sincosf(P[6], &ss, &cc);
        #pragma unroll
        for (int i = 0; i < 4; i++) {
            float px = sbx[i] * hx, py = sby[i] * hy;
            Ax[i] = px * cc - py * ss + P[0];
            Ay[i] = px * ss + py * cc + P[1];
        }
        float hx2 = 0.5f * T[3], hy2 = 0.5f * T[4];
        float ss2, cc2; __sincosf(T[6], &ss2, &cc2);
        #pragma unroll
        for (int i = 0; i < 4; i++) {
            float px = sbx[i] * hx2, py = sby[i] * hy2;
            Bx[i] = px * cc2 - py * ss2 + T[0];
            By[i] = px * ss2 + py * cc2 + T[1];
        }
    }

    // signed areas + orientation signs
    float sa = 0.f, sb = 0.f;
    #pragma unroll
    for (int i = 0; i < 4; i++) {
        int j = (i + 1) & 3;
        sa += Ax[i] * Ay[j] - Ay[i] * Ax[j];
        sb += Bx[i] * By[j] - By[i] * Bx[j];
    }
    sa *= 0.5f; sb *= 0.5f;
    float sgnA = (sa > 0.f) ? 1.f : ((sa < 0.f) ? -1.f : 0.f);
    float sgnB = (sb > 0.f) ? 1.f : ((sb < 0.f) ? -1.f : 0.f);

    // ---------------- rotated IoU via Green's theorem edge clipping ----------
    float dB[4][4], dA[4][4];
    #pragma unroll
    for (int j = 0; j < 4; j++) {
        int j1 = (j + 1) & 3;
        float ex_ = Bx[j1] - Bx[j], ey_ = By[j1] - By[j];
        #pragma unroll
        for (int i = 0; i < 4; i++)
            dB[j][i] = sgnB * (ex_ * (Ay[i] - By[j]) - ey_ * (Ax[i] - Bx[j]));
    }
    #pragma unroll
    for (int j = 0; j < 4; j++) {
        int j1 = (j + 1) & 3;
        float ex_ = Ax[j1] - Ax[j], ey_ = Ay[j1] - Ay[j];
        #pragma unroll
        for (int i = 0; i < 4; i++)
            dA[j][i] = sgnA * (ex_ * (By[i] - Ay[j]) - ey_ * (Bx[i] - Ax[j]));
    }

    float S = 0.f;
    #pragma unroll
    for (int i = 0; i < 4; i++) {
        int i1 = (i + 1) & 3;
        float t0 = 0.f, t1 = 1.f;
        #pragma unroll
        for (int j = 0; j < 4; j++) {
            float d0 = dB[j][i], d1 = dB[j][i1];
            float den = d1 - d0;
            float t = __fdividef(-d0, den);
            if (den > 0.f)       t0 = fmaxf(t0, t);
            else if (den < 0.f)  t1 = fminf(t1, t);
            else if (d0 < 0.f)   t0 = 2.f;
        }
        S += (Ax[i] * Ay[i1] - Ay[i] * Ax[i1]) * fmaxf(t1 - t0, 0.f);
    }
    #pragma unroll
    for (int i = 0; i < 4; i++) {
        int i1 = (i + 1) & 3;
        float t0 = 0.f, t1 = 1.f;
        #pragma unroll
        for (int j = 0; j < 4; j++) {
            float d0 = dA[j][i], d1 = dA[j][i1];
            float den = d1 - d0;
            float t = __fdividef(-d0, den);
            if (den > 0.f)       t0 = fmaxf(t0, t);
            else if (den < 0.f)  t1 = fminf(t1, t);
            else if (d0 < 0.f)   t0 = 2.f;
        }
        S += (Bx[i] * By[i1] - By[i] * Bx[i1]) * fmaxf(t1 - t0, 0.f);
    }
    float inter = 0.5f * fabsf(S);

    float areaA = fabsf(sa), areaB = fabsf(sb);
    float uni = areaA + areaB - inter;
    float iou = (uni > 1e-7f) ? __fdividef(inter, uni) : 0.f;

    // ---------------- DIoU-style bev loss ----------------
    float ddx = P[0] - T[0], ddy = P[1] - T[1];
    float d2 = ddx * ddx + ddy * ddy;
    float mnx = Ax[0], mxx = Ax[0], mny = Ay[0], mxy = Ay[0];
    #pragma unroll
    for (int i = 1; i < 4; i++) {
        mnx = fminf(mnx, Ax[i]); mxx = fmaxf(mxx, Ax[i]);
        mny = fminf(mny, Ay[i]); mxy = fmaxf(mxy, Ay[i]);
    }
    #pragma unroll
    for (int i = 0; i < 4; i++) {
        mnx = fminf(mnx, Bx[i]); mxx = fmaxf(mxx, Bx[i]);
        mny = fminf(mny, By[i]); mxy = fmaxf(mxy, By[i]);
    }
    float exd = mxx - mnx, eyd = mxy - mny;
    float c2 = fmaxf(exd * exd + eyd * eyd, 1e-7f);

    float atp = atanf(__fdividef(P[4], fmaxf(P[3], 1e-7f)));
    float att = atanf(__fdividef(T[4], fmaxf(T[3], 1e-7f)));
    float dv = atp - att;
    float v = 0.4052847345693511f * dv * dv;
    float alpha_c = __fdividef(v, 1.0f - iou + v + 1e-7f);
    float lbev = 1.0f - iou + __fdividef(d2, c2) + alpha_c * v;
    o[1] = lbev * pos;

    // ---------------- smooth-L1 z / h / vel ----------------
    o[2] = sl1f(P[2], T[2]) * pos;
    o[3] = sl1f(P[5], T[5]) * pos;
    o[4] = (sl1f(P[7], T[7]) + sl1f(P[8], T[8])) * pos;

    // ---------------- iou BCE ----------------
    float bce = fmaxf(xiou, 0.f) - xiou * yiou + __logf(1.0f + __expf(-fabsf(xiou)));
    o[5] = bce * pos;
    o[6] = pos;
}

__global__ __launch_bounds__(256) void bev_loss_main(
    const float* __restrict__ cls_pred, const float* __restrict__ reg_pred,
    const float* __restrict__ iou_pred, const int* __restrict__ cls_tg,
    const float* __restrict__ reg_tg, const float* __restrict__ reg_w,
    const float* __restrict__ iou_tg, double* __restrict__ part)
{
    int t  = blockIdx.x * blockDim.x + threadIdx.x;   // 0 .. 262143
    int n0 = t << 1;                                  // even pixel index
    int b  = n0 >> 16;
    int hw = n0 & 65535;

    // ---------------- vectorized loads (2 pixels) ----------------
    float2 lg2[C_];
    {
        const float* cp = cls_pred + (size_t)b * C_ * HW_ + hw;
        #pragma unroll
        for (int c = 0; c < C_; c++)
            lg2[c] = *reinterpret_cast<const float2*>(cp + (size_t)c * HW_);
    }
    float2 P2[9], T2[9];
    {
        const float* rp = reg_pred + (size_t)b * 9 * HW_ + hw;
        const float* rt = reg_tg  + (size_t)b * 9 * HW_ + hw;
        #pragma unroll
        for (int k = 0; k < 9; k++) {
            P2[k] = *reinterpret_cast<const float2*>(rp + (size_t)k * HW_);
            T2[k] = *reinterpret_cast<const float2*>(rt + (size_t)k * HW_);
        }
    }
    int2   ct2 = *reinterpret_cast<const int2*>(cls_tg + n0);
    float2 w2  = *reinterpret_cast<const float2*>(reg_w + n0);
    float2 x2  = *reinterpret_cast<const float2*>(iou_pred + n0);
    float2 y2  = *reinterpret_cast<const float2*>(iou_tg + n0);

    // ---------------- two independent pixel pipelines ----------------
    float o0[7], o1[7];
    {
        float lg[C_], P[9], T[9];
        #pragma unroll
        for (int c = 0; c < C_; c++) lg[c] = lg2[c].x;
        #pragma unroll
        for (int k = 0; k < 9; k++) { P[k] = P2[k].x; T[k] = T2[k].x; }
        pixel_loss(lg, ct2.x, P, T, w2.x, x2.x, y2.x, o0);
    }
    {
        float lg[C_], P[9], T[9];
        #pragma unroll
        for (int c = 0; c < C_; c++) lg[c] = lg2[c].y;
        #pragma unroll
        for (int k = 0; k < 9; k++) { P[k] = P2[k].y; T[k] = T2[k].y; }
        pixel_loss(lg, ct2.y, P, T, w2.y, x2.y, y2.y, o1);
    }

    // ---------------- block reduction ----------------
    __shared__ double red[4][7];
    int lane = threadIdx.x & 63;
    int wv   = threadIdx.x >> 6;
    #pragma unroll
    for (int k = 0; k < 7; k++) {
        double s = (double)o0[k] + (double)o1[k];
        for (int off = 32; off > 0; off >>= 1) s += __shfl_down(s, off, 64);
        if (lane == 0) red[wv][k] = s;
    }
    __syncthreads();
    if (threadIdx.x == 0) {
        #pragma unroll
        for (int k = 0; k < 7; k++)
            part[(size_t)blockIdx.x * 7 + k] = red[0][k] + red[1][k] + red[2][k] + red[3][k];
    }
}

__global__ void bev_loss_fin(const double* __restrict__ part, float* __restrict__ out, int nb) {
    int l = threadIdx.x;  // 64 threads
    double s[7] = { 0, 0, 0, 0, 0, 0, 0 };
    for (int i = l; i < nb; i += 64) {
        #pragma unroll
        for (int k = 0; k < 7; k++) s[k] += part[(size_t)i * 7 + k];
    }
    #pragma unroll
    for (int k = 0; k < 7; k++) {
        for (int off = 32; off > 0; off >>= 1) s[k] += __shfl_down(s[k], off, 64);
    }
    if (l == 0) {
        double npos = fmax(s[6], 1.0);
        #pragma unroll
        for (int k = 0; k < 6; k++) out[k] = (float)(s[k] / npos);
    }
}

extern "C" void kernel_launch(void* const* d_in, const int* in_sizes, int n_in,
                              void* d_out, int out_size, void* d_ws, size_t ws_size,
                              hipStream_t stream) {
    const float* cls_pred = (const float*)d_in[0];
    const float* reg_pred = (const float*)d_in[1];
    const float* iou_pred = (const float*)d_in[2];
    const int*   cls_tg   = (const int*)d_in[3];
    const float* reg_tg   = (const float*)d_in[4];
    const float* reg_w    = (const float*)d_in[5];
    const float* iou_tg   = (const float*)d_in[6];
    float* out = (float*)d_out;
    double* part = (double*)d_ws;

    const int nb = 1024;  // 1024 blocks x 256 threads x 2 px = 524288 pixels exactly
    bev_loss_main<<<nb, 256, 0, stream>>>(cls_pred, reg_pred, iou_pred, cls_tg,
                                          reg_tg, reg_w, iou_tg, part);
    bev_loss_fin<<<1, 64, 0, stream>>>(part, out, nb);
}